// Round 11
// baseline (174.508 us; speedup 1.0000x reference)
//
#include <hip/hip_runtime.h>
#include <stdint.h>

#define BATCH   2048
#define KDIM    4096
#define NDIM    11008

#define BM 256
#define BN 256
#define BK 64
#define NT (KDIM / BK)               // 64 K-tiles
#define ABYTES (BM * BK)             // 16384
#define BBYTES (BN * BK)             // 16384
#define BUF_BYTES (ABYTES + BBYTES)  // 32768
#define A_OFF 0
#define B_OFF ABYTES

typedef __attribute__((ext_vector_type(4))) int i32x4;

typedef const __attribute__((address_space(1))) char glob_char;
typedef __attribute__((address_space(3))) char lds_char;

__device__ __forceinline__ unsigned pack4(i32x4 v) {
  return  ((unsigned)v.x & 0xFFu)
        | (((unsigned)v.y & 0xFFu) << 8)
        | (((unsigned)v.z & 0xFFu) << 16)
        | (((unsigned)v.w)         << 24);
}

__global__ __launch_bounds__(256) void convert_i32_i8(const int* __restrict__ src,
                                                      unsigned* __restrict__ dst,
                                                      int n4) {
  int idx = blockIdx.x * 256 + threadIdx.x;
  if (idx >= n4) return;
  i32x4 v = ((const i32x4*)src)[idx];
  dst[idx] = pack4(v);
}

// C[2048][11008] = A[2048][4096] * W[11008][4096]^T via mfma_i32_16x16x64_i8.
// R11 = R10 geometry + m201's fine-phase schedule (the fix for 1-blk/CU):
//  - 256x256 tile (3.9e-3 staged B/op -> ~3718 TOPS staging ceiling at the
//    measured ~14.5 TB/s global->LDS service limit), G = 8x43 = 344.
//  - 8 waves (512 thr, 2m x 4n), wave-tile 128x64 = 8x4 frags, acc = 128.
//    __launch_bounds__(512,2): R9 lesson - never force 3 waves/SIMD with a
//    128-reg accumulator (spill); R10 confirmed no spill at (512,2).
//  - 3 rotating 32KB buffers (96 KB LDS, 1 block/CU), depth-2 prefetch.
//  - 4 phases per KT (m201 port): each = {ds_read this phase's frags ||
//    issue 1 staging gload -> s_barrier -> setprio(1) + 8 MFMA + setprio(0)
//    -> s_barrier}; snaked quadrants (A0-3xB01, A0-3xB23, A4-7xB23,
//    A4-7xB01) so phases add only 2-4 new frags. ONE counted vmcnt(4) in
//    P3 (after all 4 issues; retires tile t+1's 4 loads, t+2's stay in
//    flight - the pipe never drains). No manual lgkmcnt/sched_barrier
//    (R6 regression lesson; compiler emits fine-grained lgkm waits).
//  - XCD raster: mt = wg/43 -> each XCD permanently owns ONE mt (1 MB
//    A-panel stays L2-resident); nt = wg%43 walks B-panels.
// Slot swizzle (validated 0-conflict): 64B rows, physical 16B slot
// p = logical ^ ((row>>1)&3); applied on global SOURCE (linear LDS dest)
// and on the ds_read address.
__global__ __launch_bounds__(512, 2) void ternary_gemm(const char* __restrict__ A8,
                                                       const char* __restrict__ B8,
                                                       const float* __restrict__ scale,
                                                       const float* __restrict__ bias,
                                                       float* __restrict__ out) {
  __shared__ char lds[3 * BUF_BYTES];   // 98304 B -> 1 block/CU

  const int tid  = threadIdx.x;
  const int wid  = tid >> 6;
  const int lane = tid & 63;

  // XCD swizzle (344 % 8 == 0 -> bijective) + mt-per-XCD raster
  const int wg = (blockIdx.x & 7) * 43 + (blockIdx.x >> 3);
  const int mt = wg / 43;               // 0..7  : one A-panel per XCD
  const int nt = wg % 43;               // 0..42
  const int arow0 = mt * BM;
  const int brow0 = nt * BN;

  const int wr = wid >> 2;              // 0..1 : 128-row half
  const int wc = wid & 3;               // 0..3 : 64-col quarter
  const int rsub = lane & 15;
  const int sgrp = lane >> 4;           // k-slot 0..3 (16 i8 each)

  // staging: 512 thr x 16B = 8KB/round = 128 rows; A rounds 0-1, B rounds 0-1
  const int srow  = tid >> 2;           // 0..127
  const int sslot = (tid & 3) ^ ((srow >> 1) & 3);  // +r*128 preserves (row>>1)&3
  const char* gA0 = A8 + (size_t)(arow0       + srow) * KDIM + sslot * 16;
  const char* gA1 = A8 + (size_t)(arow0 + 128 + srow) * KDIM + sslot * 16;
  const char* gB0 = B8 + (size_t)(brow0       + srow) * KDIM + sslot * 16;
  const char* gB1 = B8 + (size_t)(brow0 + 128 + srow) * KDIM + sslot * 16;

  auto stage = [&](const char* g, int bufo, int kt, int dsto) {
    __builtin_amdgcn_global_load_lds((glob_char*)(g + kt * BK),
        (lds_char*)(lds + bufo + dsto + wid * 1024), 16, 0, 0);
  };

  // loop-invariant fragment byte-offsets (0-conflict pattern)
  int offA[8], offB[4];
#pragma unroll
  for (int m = 0; m < 8; ++m) {
    const int row = wr * 128 + m * 16 + rsub;
    const int p   = sgrp ^ ((row >> 1) & 3);
    offA[m] = A_OFF + row * 64 + p * 16;
  }
#pragma unroll
  for (int n = 0; n < 4; ++n) {
    const int row = wc * 64 + n * 16 + rsub;
    const int p   = sgrp ^ ((row >> 1) & 3);
    offB[n] = B_OFF + row * 64 + p * 16;
  }

  i32x4 acc[8][4];
#pragma unroll
  for (int m = 0; m < 8; ++m)
#pragma unroll
    for (int n = 0; n < 4; ++n)
      acc[m][n] = (i32x4){0, 0, 0, 0};

  int cur = 0, nxt = BUF_BYTES, pf = 2 * BUF_BYTES;

  // prologue: stage tiles 0 and 1 in loop issue order (A0,A1,B0,B1)
  stage(gA0, cur, 0, A_OFF);  stage(gA1, cur, 0, A_OFF + 8192);
  stage(gB0, cur, 0, B_OFF);  stage(gB1, cur, 0, B_OFF + 8192);
  stage(gA0, nxt, 1, A_OFF);  stage(gA1, nxt, 1, A_OFF + 8192);
  stage(gB0, nxt, 1, B_OFF);  stage(gB1, nxt, 1, B_OFF + 8192);
  asm volatile("s_waitcnt vmcnt(4)" ::: "memory");   // tile 0 landed
  __builtin_amdgcn_s_barrier();

  for (int t = 0; t < NT; ++t) {
    const int kt2 = (t + 2 < NT) ? t + 2 : NT - 1;   // clamped dummy at tail

    i32x4 a0, a1, a2, a3, a4, a5, a6, a7, b0, b1, b2, b3;

    // ---- P0: read A0-3,B0,B1 ; stage A r0 ; A0-3 x B0-1 ----
    a0 = *(const i32x4*)(lds + cur + offA[0]);
    a1 = *(const i32x4*)(lds + cur + offA[1]);
    a2 = *(const i32x4*)(lds + cur + offA[2]);
    a3 = *(const i32x4*)(lds + cur + offA[3]);
    b0 = *(const i32x4*)(lds + cur + offB[0]);
    b1 = *(const i32x4*)(lds + cur + offB[1]);
    stage(gA0, pf, kt2, A_OFF);
    __builtin_amdgcn_s_barrier();
    __builtin_amdgcn_s_setprio(1);
    acc[0][0] = __builtin_amdgcn_mfma_i32_16x16x64_i8(a0, b0, acc[0][0], 0, 0, 0);
    acc[1][0] = __builtin_amdgcn_mfma_i32_16x16x64_i8(a1, b0, acc[1][0], 0, 0, 0);
    acc[2][0] = __builtin_amdgcn_mfma_i32_16x16x64_i8(a2, b0, acc[2][0], 0, 0, 0);
    acc[3][0] = __builtin_amdgcn_mfma_i32_16x16x64_i8(a3, b0, acc[3][0], 0, 0, 0);
    acc[0][1] = __builtin_amdgcn_mfma_i32_16x16x64_i8(a0, b1, acc[0][1], 0, 0, 0);
    acc[1][1] = __builtin_amdgcn_mfma_i32_16x16x64_i8(a1, b1, acc[1][1], 0, 0, 0);
    acc[2][1] = __builtin_amdgcn_mfma_i32_16x16x64_i8(a2, b1, acc[2][1], 0, 0, 0);
    acc[3][1] = __builtin_amdgcn_mfma_i32_16x16x64_i8(a3, b1, acc[3][1], 0, 0, 0);
    __builtin_amdgcn_s_setprio(0);
    __builtin_amdgcn_s_barrier();

    // ---- P1: read B2,B3 ; stage A r1 ; A0-3 x B2-3 ----
    b2 = *(const i32x4*)(lds + cur + offB[2]);
    b3 = *(const i32x4*)(lds + cur + offB[3]);
    stage(gA1, pf, kt2, A_OFF + 8192);
    __builtin_amdgcn_s_barrier();
    __builtin_amdgcn_s_setprio(1);
    acc[0][2] = __builtin_amdgcn_mfma_i32_16x16x64_i8(a0, b2, acc[0][2], 0, 0, 0);
    acc[1][2] = __builtin_amdgcn_mfma_i32_16x16x64_i8(a1, b2, acc[1][2], 0, 0, 0);
    acc[2][2] = __builtin_amdgcn_mfma_i32_16x16x64_i8(a2, b2, acc[2][2], 0, 0, 0);
    acc[3][2] = __builtin_amdgcn_mfma_i32_16x16x64_i8(a3, b2, acc[3][2], 0, 0, 0);
    acc[0][3] = __builtin_amdgcn_mfma_i32_16x16x64_i8(a0, b3, acc[0][3], 0, 0, 0);
    acc[1][3] = __builtin_amdgcn_mfma_i32_16x16x64_i8(a1, b3, acc[1][3], 0, 0, 0);
    acc[2][3] = __builtin_amdgcn_mfma_i32_16x16x64_i8(a2, b3, acc[2][3], 0, 0, 0);
    acc[3][3] = __builtin_amdgcn_mfma_i32_16x16x64_i8(a3, b3, acc[3][3], 0, 0, 0);
    __builtin_amdgcn_s_setprio(0);
    __builtin_amdgcn_s_barrier();

    // ---- P2: read A4-7 ; stage B r0 ; A4-7 x B2-3 ----
    a4 = *(const i32x4*)(lds + cur + offA[4]);
    a5 = *(const i32x4*)(lds + cur + offA[5]);
    a6 = *(const i32x4*)(lds + cur + offA[6]);
    a7 = *(const i32x4*)(lds + cur + offA[7]);
    stage(gB0, pf, kt2, B_OFF);
    __builtin_amdgcn_s_barrier();
    __builtin_amdgcn_s_setprio(1);
    acc[4][2] = __builtin_amdgcn_mfma_i32_16x16x64_i8(a4, b2, acc[4][2], 0, 0, 0);
    acc[5][2] = __builtin_amdgcn_mfma_i32_16x16x64_i8(a5, b2, acc[5][2], 0, 0, 0);
    acc[6][2] = __builtin_amdgcn_mfma_i32_16x16x64_i8(a6, b2, acc[6][2], 0, 0, 0);
    acc[7][2] = __builtin_amdgcn_mfma_i32_16x16x64_i8(a7, b2, acc[7][2], 0, 0, 0);
    acc[4][3] = __builtin_amdgcn_mfma_i32_16x16x64_i8(a4, b3, acc[4][3], 0, 0, 0);
    acc[5][3] = __builtin_amdgcn_mfma_i32_16x16x64_i8(a5, b3, acc[5][3], 0, 0, 0);
    acc[6][3] = __builtin_amdgcn_mfma_i32_16x16x64_i8(a6, b3, acc[6][3], 0, 0, 0);
    acc[7][3] = __builtin_amdgcn_mfma_i32_16x16x64_i8(a7, b3, acc[7][3], 0, 0, 0);
    __builtin_amdgcn_s_setprio(0);
    __builtin_amdgcn_s_barrier();

    // ---- P3: stage B r1 ; vmcnt(4) -> tile t+1 landed (t+2's 4 in flight);
    //          A4-7 x B0-1 ----
    stage(gB1, pf, kt2, B_OFF + 8192);
    asm volatile("s_waitcnt vmcnt(4)" ::: "memory");
    __builtin_amdgcn_s_barrier();
    __builtin_amdgcn_s_setprio(1);
    acc[4][0] = __builtin_amdgcn_mfma_i32_16x16x64_i8(a4, b0, acc[4][0], 0, 0, 0);
    acc[5][0] = __builtin_amdgcn_mfma_i32_16x16x64_i8(a5, b0, acc[5][0], 0, 0, 0);
    acc[6][0] = __builtin_amdgcn_mfma_i32_16x16x64_i8(a6, b0, acc[6][0], 0, 0, 0);
    acc[7][0] = __builtin_amdgcn_mfma_i32_16x16x64_i8(a7, b0, acc[7][0], 0, 0, 0);
    acc[4][1] = __builtin_amdgcn_mfma_i32_16x16x64_i8(a4, b1, acc[4][1], 0, 0, 0);
    acc[5][1] = __builtin_amdgcn_mfma_i32_16x16x64_i8(a5, b1, acc[5][1], 0, 0, 0);
    acc[6][1] = __builtin_amdgcn_mfma_i32_16x16x64_i8(a6, b1, acc[6][1], 0, 0, 0);
    acc[7][1] = __builtin_amdgcn_mfma_i32_16x16x64_i8(a7, b1, acc[7][1], 0, 0, 0);
    __builtin_amdgcn_s_setprio(0);
    __builtin_amdgcn_s_barrier();

    const int tb = cur; cur = nxt; nxt = pf; pf = tb;
  }

  // Epilogue (validated R1-R10): C/D col = lane&15, row = (lane>>4)*4 + reg
  const int crow = sgrp * 4;
#pragma unroll
  for (int n = 0; n < 4; ++n) {
    const int col = brow0 + wc * 64 + n * 16 + rsub;
    const float sc = scale[col];
    const float bs = bias[col];
#pragma unroll
    for (int m = 0; m < 8; ++m) {
      const int r0 = arow0 + wr * 128 + m * 16 + crow;
#pragma unroll
      for (int j = 0; j < 4; ++j) {
        out[(size_t)(r0 + j) * NDIM + col] = (float)acc[m][n][j] * sc + bs;
      }
    }
  }
}

extern "C" void kernel_launch(void* const* d_in, const int* in_sizes, int n_in,
                              void* d_out, int out_size, void* d_ws, size_t ws_size,
                              hipStream_t stream) {
  const int*   input  = (const int*)d_in[0];     // [2048][4096] int32
  const int*   weight = (const int*)d_in[1];     // [11008][4096] int32 in {-1,0,1}
  const float* scale  = (const float*)d_in[2];   // [11008]
  const float* bias   = (const float*)d_in[3];   // [11008]
  float*       out    = (float*)d_out;           // [2048][11008] fp32

  const size_t needA = (size_t)BATCH * KDIM;     // 8 MB int8
  const size_t needB = (size_t)NDIM * KDIM;      // 44 MB int8

  char* A8 = (char*)d_ws;
  char* B8 = A8 + needA;
  const int nA4 = (int)(needA / 4);
  const int nB4 = (int)(needB / 4);
  convert_i32_i8<<<(nA4 + 255) / 256, 256, 0, stream>>>(input, (unsigned*)A8, nA4);
  convert_i32_i8<<<(nB4 + 255) / 256, 256, 0, stream>>>(weight, (unsigned*)B8, nB4);

  const dim3 grid((BATCH / BM) * (NDIM / BN));   // 8 * 43 = 344
  const dim3 block(512);
  ternary_gemm<<<grid, block, 0, stream>>>(A8, B8, scale, bias, out);
  (void)ws_size; (void)n_in; (void)in_sizes; (void)out_size;
}

// Round 12
// 147.933 us; speedup vs baseline: 1.1796x; 1.1796x over previous
//
#include <hip/hip_runtime.h>
#include <stdint.h>

#define BATCH   2048
#define KDIM    4096
#define NDIM    11008

#define BM 128
#define BN 128
#define BK 128
#define NT (KDIM / BK)               // 32 K-tiles
#define ABYTES (BM * BK)             // 16384 (int8)
#define BBYTES (BN * BK / 4)         // 4096  (2-bit packed)
#define BUF_BYTES (ABYTES + BBYTES)  // 20480
#define A_OFF 0
#define B_OFF ABYTES
#define BPK_ROWB 1024                // packed B row bytes = KDIM/4

typedef __attribute__((ext_vector_type(4))) int i32x4;

typedef const __attribute__((address_space(1))) char glob_char;
typedef __attribute__((address_space(3))) char lds_char;

__device__ __forceinline__ unsigned pack4(i32x4 v) {
  return  ((unsigned)v.x & 0xFFu)
        | (((unsigned)v.y & 0xFFu) << 8)
        | (((unsigned)v.z & 0xFFu) << 16)
        | (((unsigned)v.w)         << 24);
}

// A: int32 (values in [-128,127]) -> packed int8, 4 elements per thread
__global__ __launch_bounds__(256) void convert_i32_i8(const int* __restrict__ src,
                                                      unsigned* __restrict__ dst,
                                                      int n4) {
  int idx = blockIdx.x * 256 + threadIdx.x;
  if (idx >= n4) return;
  i32x4 v = ((const i32x4*)src)[idx];
  dst[idx] = pack4(v);
}

// B: ternary int32 -> 2-bit packed, 16 elements per thread -> one u32.
// Bit layout: element e at bits [8*(e&3) + 2*(e>>2)] so that decode word j
// (elements 4j..4j+3) = sign2((w >> 2j) & 0x03030303).
// LDS bank swizzle BAKED IN: within each 32B group (8 words), word i%8 is
// stored at slot (i%8) ^ (row & 7)  -> GEMM stages with a pure linear
// global_load_lds copy and ds_reads with the same formula (rule 21).
__global__ __launch_bounds__(256) void convert_w2(const int* __restrict__ src,
                                                  unsigned* __restrict__ dst) {
  const int f = blockIdx.x * 256 + threadIdx.x;   // < 11008*256
  const int r = f >> 8;                           // row 0..11007
  const int i = f & 255;                          // word-in-row 0..255
  const int* p = src + (size_t)r * KDIM + i * 16;
  unsigned w = 0;
#pragma unroll
  for (int e = 0; e < 16; ++e) {
    const unsigned v = (unsigned)p[e] & 3u;       // -1->3, 0->0, 1->1
    w |= v << (8 * (e & 3) + 2 * (e >> 2));
  }
  const int slot = (i & 7) ^ (r & 7);
  dst[(size_t)r * 256 + (i >> 3) * 8 + slot] = w;
}

// decode 16x 2-bit ternary -> i32x4 of 16 int8 (k-order).
// per byte: {0,1,3} -> {0x00,0x01,0xFF}: (v&1) | ((v&2)*0x7F)
// (0x02*0x7F = 0xFE stays in-byte; no cross-byte carry, unlike xor-sub).
__device__ __forceinline__ i32x4 dec2(unsigned w) {
  const unsigned M1 = 0x01010101u, M2 = 0x02020202u;
  i32x4 r;
  unsigned x;
  x = w;      r.x = (int)((x & M1) | ((x & M2) * 0x7Fu));
  x = w >> 2; r.y = (int)((x & M1) | ((x & M2) * 0x7Fu));
  x = w >> 4; r.z = (int)((x & M1) | ((x & M2) * 0x7Fu));
  x = w >> 6; r.w = (int)((x & M1) | ((x & M2) * 0x7Fu));
  return r;
}

// C[2048][11008] = A[2048][4096] * W[11008][4096]^T via mfma_i32_16x16x64_i8.
// R12: 2-bit-packed B. 128x128 tile, BK=128, staged/KT = A 16KB + B 4KB =
// 20KB -> 4.77e-3 B/op -> staging-service ceiling ~3040 TOPS (vs R7's 1859
// at int8 B). G = 16x86 = 1376, 40KB LDS dbuf + ~150 regs -> 3 blocks/CU
// -> 89.6% tail eff (the two-factor model: rate = steady x tail).
// Skeleton = R7 (validated 103% of its ceiling): barrier-free double
// buffer, stage-next at iter top, ONE vmcnt(0)+s_barrier per KT128,
// 32 MFMA/wave between barriers, no manual lgkmcnt/sched_barrier.
// A slot swizzle (R7-validated 0-conflict): 128B rows, 16B slot
// p = (ks*4+sgrp) ^ (row&7), pre-applied on the global source.
// B swizzle baked into packed layout by convert_w2 (see above);
// b32 frag reads land 2-way max (free).
__global__ __launch_bounds__(256, 3) void ternary_gemm(const char* __restrict__ A8,
                                                       const unsigned* __restrict__ B2,
                                                       const float* __restrict__ scale,
                                                       const float* __restrict__ bias,
                                                       float* __restrict__ out) {
  __shared__ char lds[2 * BUF_BYTES];   // 40960 B -> 3 blocks/CU

  const int tid  = threadIdx.x;
  const int wid  = tid >> 6;
  const int lane = tid & 63;

  // XCD swizzle (1376 % 8 == 0 -> bijective) + 4-wide mt-supertile raster:
  // each XCD chunk (172 contiguous wg) = 4 A-panels (2 MB, L2-resident) x 43 nt
  const int wg  = (blockIdx.x & 7) * 172 + (blockIdx.x >> 3);
  const int mtq = wg / 344;             // 0..3
  const int r   = wg - mtq * 344;       // 0..343
  const int nt  = r >> 2;               // 0..85
  const int mt  = mtq * 4 + (r & 3);    // 0..15
  const int arow0 = mt * BM;
  const int brow0 = nt * BN;

  const int wr = wid >> 1;              // 0..1 : 64-row half
  const int wc = wid & 1;               // 0..1 : 64-col half
  const int rsub = lane & 15;
  const int sgrp = lane >> 4;           // k-slot-in-64 (16 i8 each)

  // A staging: 4 rounds of 256 thr x 16B = 4KB (32 rows of 128B)
  const int srowA = tid >> 3;           // 0..31
  const int slotA = (tid & 7) ^ (srowA & 7);
  // B staging: 1 round of 256 thr x 16B = 4KB (128 rows of 32B), linear copy
  const int srowB = tid >> 1;           // 0..127
  const int shalfB = (tid & 1) * 16;

  auto stage_tile = [&](int bufo, int kt) {
#pragma unroll
    for (int rr = 0; rr < 4; ++rr) {
      __builtin_amdgcn_global_load_lds(
          (glob_char*)(A8 + (size_t)(arow0 + rr * 32 + srowA) * KDIM + kt * BK + slotA * 16),
          (lds_char*)(lds + bufo + A_OFF + rr * 4096 + wid * 1024), 16, 0, 0);
    }
    __builtin_amdgcn_global_load_lds(
        (glob_char*)((const char*)B2 + (size_t)(brow0 + srowB) * BPK_ROWB + kt * (BK / 4) + shalfB),
        (lds_char*)(lds + bufo + B_OFF + wid * 1024), 16, 0, 0);
  };

  // loop-invariant fragment byte-offsets
  int offA[4][2], offB[4][2];
#pragma unroll
  for (int m = 0; m < 4; ++m) {
    const int row = wr * 64 + m * 16 + rsub;
#pragma unroll
    for (int ks = 0; ks < 2; ++ks) {
      const int p = (ks * 4 + sgrp) ^ (row & 7);
      offA[m][ks] = A_OFF + row * 128 + p * 16;
    }
  }
#pragma unroll
  for (int n = 0; n < 4; ++n) {
    const int row = wc * 64 + n * 16 + rsub;
#pragma unroll
    for (int ks = 0; ks < 2; ++ks) {
      const int p = (ks * 4 + sgrp) ^ (row & 7);
      offB[n][ks] = B_OFF + row * 32 + p * 4;
    }
  }

  i32x4 acc[4][4];
#pragma unroll
  for (int m = 0; m < 4; ++m)
#pragma unroll
    for (int n = 0; n < 4; ++n)
      acc[m][n] = (i32x4){0, 0, 0, 0};

  int cur = 0, nxt = BUF_BYTES;

  // prologue: stage tile 0, drain, barrier
  stage_tile(cur, 0);
  asm volatile("s_waitcnt vmcnt(0)" ::: "memory");
  __builtin_amdgcn_s_barrier();

  for (int t = 0; t < NT; ++t) {
    const int kt1 = (t + 1 < NT) ? t + 1 : NT - 1;   // clamped tail re-stage

    // issue next tile's 5 staging loads first (earliest HBM start)
    stage_tile(nxt, kt1);

#pragma unroll
    for (int ks = 0; ks < 2; ++ks) {
      i32x4 a0 = *(const i32x4*)(lds + cur + offA[0][ks]);
      i32x4 a1 = *(const i32x4*)(lds + cur + offA[1][ks]);
      i32x4 a2 = *(const i32x4*)(lds + cur + offA[2][ks]);
      i32x4 a3 = *(const i32x4*)(lds + cur + offA[3][ks]);
      unsigned w0 = *(const unsigned*)(lds + cur + offB[0][ks]);
      unsigned w1 = *(const unsigned*)(lds + cur + offB[1][ks]);
      unsigned w2 = *(const unsigned*)(lds + cur + offB[2][ks]);
      unsigned w3 = *(const unsigned*)(lds + cur + offB[3][ks]);
      i32x4 b0 = dec2(w0);
      i32x4 b1 = dec2(w1);
      i32x4 b2 = dec2(w2);
      i32x4 b3 = dec2(w3);
      __builtin_amdgcn_s_setprio(1);
      acc[0][0] = __builtin_amdgcn_mfma_i32_16x16x64_i8(a0, b0, acc[0][0], 0, 0, 0);
      acc[1][0] = __builtin_amdgcn_mfma_i32_16x16x64_i8(a1, b0, acc[1][0], 0, 0, 0);
      acc[2][0] = __builtin_amdgcn_mfma_i32_16x16x64_i8(a2, b0, acc[2][0], 0, 0, 0);
      acc[3][0] = __builtin_amdgcn_mfma_i32_16x16x64_i8(a3, b0, acc[3][0], 0, 0, 0);
      acc[0][1] = __builtin_amdgcn_mfma_i32_16x16x64_i8(a0, b1, acc[0][1], 0, 0, 0);
      acc[1][1] = __builtin_amdgcn_mfma_i32_16x16x64_i8(a1, b1, acc[1][1], 0, 0, 0);
      acc[2][1] = __builtin_amdgcn_mfma_i32_16x16x64_i8(a2, b1, acc[2][1], 0, 0, 0);
      acc[3][1] = __builtin_amdgcn_mfma_i32_16x16x64_i8(a3, b1, acc[3][1], 0, 0, 0);
      acc[0][2] = __builtin_amdgcn_mfma_i32_16x16x64_i8(a0, b2, acc[0][2], 0, 0, 0);
      acc[1][2] = __builtin_amdgcn_mfma_i32_16x16x64_i8(a1, b2, acc[1][2], 0, 0, 0);
      acc[2][2] = __builtin_amdgcn_mfma_i32_16x16x64_i8(a2, b2, acc[2][2], 0, 0, 0);
      acc[3][2] = __builtin_amdgcn_mfma_i32_16x16x64_i8(a3, b2, acc[3][2], 0, 0, 0);
      acc[0][3] = __builtin_amdgcn_mfma_i32_16x16x64_i8(a0, b3, acc[0][3], 0, 0, 0);
      acc[1][3] = __builtin_amdgcn_mfma_i32_16x16x64_i8(a1, b3, acc[1][3], 0, 0, 0);
      acc[2][3] = __builtin_amdgcn_mfma_i32_16x16x64_i8(a2, b3, acc[2][3], 0, 0, 0);
      acc[3][3] = __builtin_amdgcn_mfma_i32_16x16x64_i8(a3, b3, acc[3][3], 0, 0, 0);
      __builtin_amdgcn_s_setprio(0);
    }

    // next tile landed; publish block-wide, then swap
    asm volatile("s_waitcnt vmcnt(0)" ::: "memory");
    __builtin_amdgcn_s_barrier();

    const int tb = cur; cur = nxt; nxt = tb;
  }

  // Epilogue (validated R1-R11): C/D col = lane&15, row = (lane>>4)*4 + reg
  const int crow = sgrp * 4;
#pragma unroll
  for (int n = 0; n < 4; ++n) {
    const int col = brow0 + wc * 64 + n * 16 + rsub;
    const float sc = scale[col];
    const float bs = bias[col];
#pragma unroll
    for (int m = 0; m < 4; ++m) {
      const int r0 = arow0 + wr * 64 + m * 16 + crow;
#pragma unroll
      for (int j = 0; j < 4; ++j) {
        out[(size_t)(r0 + j) * NDIM + col] = (float)acc[m][n][j] * sc + bs;
      }
    }
  }
}

extern "C" void kernel_launch(void* const* d_in, const int* in_sizes, int n_in,
                              void* d_out, int out_size, void* d_ws, size_t ws_size,
                              hipStream_t stream) {
  const int*   input  = (const int*)d_in[0];     // [2048][4096] int32
  const int*   weight = (const int*)d_in[1];     // [11008][4096] int32 in {-1,0,1}
  const float* scale  = (const float*)d_in[2];   // [11008]
  const float* bias   = (const float*)d_in[3];   // [11008]
  float*       out    = (float*)d_out;           // [2048][11008] fp32

  const size_t needA = (size_t)BATCH * KDIM;          // 8 MB int8
  const size_t needB = (size_t)NDIM * BPK_ROWB;       // 11 MB 2-bit packed

  char*     A8  = (char*)d_ws;
  unsigned* Bpk = (unsigned*)(A8 + needA);
  const int nA4 = (int)(needA / 4);
  convert_i32_i8<<<(nA4 + 255) / 256, 256, 0, stream>>>(input, (unsigned*)A8, nA4);
  convert_w2<<<NDIM * (KDIM / 16) / 256, 256, 0, stream>>>(weight, Bpk);

  const dim3 grid((BATCH / BM) * (NDIM / BN));   // 16 * 86 = 1376
  const dim3 block(256);
  ternary_gemm<<<grid, block, 0, stream>>>(A8, Bpk, scale, bias, out);
  (void)ws_size; (void)n_in; (void)in_sizes; (void)out_size; (void)needB;
}

// Round 13
// 140.500 us; speedup vs baseline: 1.2420x; 1.0529x over previous
//
#include <hip/hip_runtime.h>
#include <stdint.h>

#define BATCH   2048
#define KDIM    4096
#define NDIM    11008

#define BM 128
#define BN 128
#define BK 128
#define NT (KDIM / BK)               // 32 K-tiles
#define ABYTES (BM * BK)             // 16384 (int8)
#define BBYTES (BN * BK / 4)         // 4096  (2-bit packed)
#define BUF_BYTES (ABYTES + BBYTES)  // 20480
#define A_OFF 0
#define B_OFF ABYTES
#define BPK_ROWB 1024                // packed B row bytes = KDIM/4

typedef __attribute__((ext_vector_type(4))) int i32x4;

typedef const __attribute__((address_space(1))) char glob_char;
typedef __attribute__((address_space(3))) char lds_char;

__device__ __forceinline__ unsigned pack4(i32x4 v) {
  return  ((unsigned)v.x & 0xFFu)
        | (((unsigned)v.y & 0xFFu) << 8)
        | (((unsigned)v.z & 0xFFu) << 16)
        | (((unsigned)v.w)         << 24);
}

// A: int32 (values in [-128,127]) -> packed int8, 4 elements per thread
__global__ __launch_bounds__(256) void convert_i32_i8(const int* __restrict__ src,
                                                      unsigned* __restrict__ dst,
                                                      int n4) {
  int idx = blockIdx.x * 256 + threadIdx.x;
  if (idx >= n4) return;
  i32x4 v = ((const i32x4*)src)[idx];
  dst[idx] = pack4(v);
}

// B: ternary int32 -> 2-bit packed, 16 elements per thread -> one u32.
// Element e at bits [8*(e&3) + 2*(e>>2)] so decode word j (elems 4j..4j+3)
// = sign2((w >> 2j) & 0x03030303).
// LDS bank swizzle BAKED IN: within each 32B group (8 words), word i%8
// stored at slot (i%8) ^ (row&7) -> GEMM stages with pure linear
// global_load_lds and ds_reads with the same XOR (rule 21).
__global__ __launch_bounds__(256) void convert_w2(const int* __restrict__ src,
                                                  unsigned* __restrict__ dst) {
  const int f = blockIdx.x * 256 + threadIdx.x;   // < 11008*256
  const int r = f >> 8;                           // row 0..11007
  const int i = f & 255;                          // word-in-row 0..255
  const int* p = src + (size_t)r * KDIM + i * 16;
  unsigned w = 0;
#pragma unroll
  for (int e = 0; e < 16; ++e) {
    const unsigned v = (unsigned)p[e] & 3u;       // -1->3, 0->0, 1->1
    w |= v << (8 * (e & 3) + 2 * (e >> 2));
  }
  const int slot = (i & 7) ^ (r & 7);
  dst[(size_t)r * 256 + (i >> 3) * 8 + slot] = w;
}

// decode 16x 2-bit ternary -> i32x4 of 16 int8 (k-order).
// per byte {0,1,3} -> {0x00,0x01,0xFF}: (x&M1) | ((x&M2)*0x7F), with the
// multiply strength-reduced to (y<<7)-y explicitly (no v_mul_lo_u32).
__device__ __forceinline__ i32x4 dec2(unsigned w) {
  const unsigned M1 = 0x01010101u, M2 = 0x02020202u;
  i32x4 r;
  {
    unsigned x = w;      unsigned y = x & M2; r.x = (int)((x & M1) | ((y << 7) - y));
  }
  {
    unsigned x = w >> 2; unsigned y = x & M2; r.y = (int)((x & M1) | ((y << 7) - y));
  }
  {
    unsigned x = w >> 4; unsigned y = x & M2; r.z = (int)((x & M1) | ((y << 7) - y));
  }
  {
    unsigned x = w >> 6; unsigned y = x & M2; r.w = (int)((x & M1) | ((y << 7) - y));
  }
  return r;
}

// C[2048][11008] = A[2048][4096] * W[11008][4096]^T via mfma_i32_16x16x64_i8.
// R13 = R12 with a 1m x 4n wave grid (wave-tile 128x32):
//  - each wave OWNS a 32-col B slice -> every packed B word decoded exactly
//    once per block (1024 word-decodes/block-KT vs R12's 2048; decode was
//    R12's new limiter: VALUBusy 53%, steady 1917 vs 3040 ceiling).
//  - A frags/wave double to 16 b128/KT (LDS-read ~65KB/block-KT, well under
//    the wall at either 85 or 128 B/cy/CU).
//  - acc[8][2] = 64 regs -> safe at __launch_bounds__(256,3) (R9 lesson).
// Everything else identical to R12: 2-bit packed B (staged 20KB/KT ->
// 4.77e-3 B/op -> 3040 TOPS staging ceiling), G=16x86=1376, 40KB LDS dbuf
// -> 3 blocks/CU, R7 barrier-free skeleton (stage-next at iter top, ONE
// vmcnt(0)+s_barrier per KT128), A 8-slot swizzle on global source,
// B swizzle baked into packed layout, 4-wide mt-supertile XCD raster.
__global__ __launch_bounds__(256, 3) void ternary_gemm(const char* __restrict__ A8,
                                                       const unsigned* __restrict__ B2,
                                                       const float* __restrict__ scale,
                                                       const float* __restrict__ bias,
                                                       float* __restrict__ out) {
  __shared__ char lds[2 * BUF_BYTES];   // 40960 B -> 3 blocks/CU

  const int tid  = threadIdx.x;
  const int wid  = tid >> 6;
  const int lane = tid & 63;

  // XCD swizzle (1376 % 8 == 0 -> bijective) + 4-wide mt-supertile raster
  const int wg  = (blockIdx.x & 7) * 172 + (blockIdx.x >> 3);
  const int mtq = wg / 344;             // 0..3
  const int r   = wg - mtq * 344;       // 0..343
  const int nt  = r >> 2;               // 0..85
  const int mt  = mtq * 4 + (r & 3);    // 0..15
  const int arow0 = mt * BM;
  const int brow0 = nt * BN;

  const int wc = wid;                   // 0..3 : 32-col slice (unique B per wave)
  const int rsub = lane & 15;
  const int sgrp = lane >> 4;           // k-slot-in-64 (16 i8 each)

  // A staging: 4 rounds of 256 thr x 16B = 4KB (32 rows of 128B)
  const int srowA = tid >> 3;           // 0..31
  const int slotA = (tid & 7) ^ (srowA & 7);
  // B staging: 1 round of 256 thr x 16B (128 rows of 32B), linear copy
  const int srowB = tid >> 1;           // 0..127
  const int shalfB = (tid & 1) * 16;

  auto stage_tile = [&](int bufo, int kt) {
#pragma unroll
    for (int rr = 0; rr < 4; ++rr) {
      __builtin_amdgcn_global_load_lds(
          (glob_char*)(A8 + (size_t)(arow0 + rr * 32 + srowA) * KDIM + kt * BK + slotA * 16),
          (lds_char*)(lds + bufo + A_OFF + rr * 4096 + wid * 1024), 16, 0, 0);
    }
    __builtin_amdgcn_global_load_lds(
        (glob_char*)((const char*)B2 + (size_t)(brow0 + srowB) * BPK_ROWB + kt * (BK / 4) + shalfB),
        (lds_char*)(lds + bufo + B_OFF + wid * 1024), 16, 0, 0);
  };

  // loop-invariant fragment byte-offsets
  int offA[8][2], offB[2][2];
#pragma unroll
  for (int m = 0; m < 8; ++m) {
    const int row = m * 16 + rsub;      // all 128 rows (1m wave grid)
#pragma unroll
    for (int ks = 0; ks < 2; ++ks) {
      const int p = (ks * 4 + sgrp) ^ (row & 7);
      offA[m][ks] = A_OFF + row * 128 + p * 16;
    }
  }
#pragma unroll
  for (int n = 0; n < 2; ++n) {
    const int row = wc * 32 + n * 16 + rsub;
#pragma unroll
    for (int ks = 0; ks < 2; ++ks) {
      const int p = (ks * 4 + sgrp) ^ (row & 7);
      offB[n][ks] = B_OFF + row * 32 + p * 4;
    }
  }

  i32x4 acc[8][2];
#pragma unroll
  for (int m = 0; m < 8; ++m)
#pragma unroll
    for (int n = 0; n < 2; ++n)
      acc[m][n] = (i32x4){0, 0, 0, 0};

  int cur = 0, nxt = BUF_BYTES;

  // prologue: stage tile 0, drain, barrier
  stage_tile(cur, 0);
  asm volatile("s_waitcnt vmcnt(0)" ::: "memory");
  __builtin_amdgcn_s_barrier();

  for (int t = 0; t < NT; ++t) {
    const int kt1 = (t + 1 < NT) ? t + 1 : NT - 1;   // clamped tail re-stage

    // issue next tile's 5 staging loads first (earliest HBM start)
    stage_tile(nxt, kt1);

#pragma unroll
    for (int ks = 0; ks < 2; ++ks) {
      i32x4 a0 = *(const i32x4*)(lds + cur + offA[0][ks]);
      i32x4 a1 = *(const i32x4*)(lds + cur + offA[1][ks]);
      i32x4 a2 = *(const i32x4*)(lds + cur + offA[2][ks]);
      i32x4 a3 = *(const i32x4*)(lds + cur + offA[3][ks]);
      i32x4 a4 = *(const i32x4*)(lds + cur + offA[4][ks]);
      i32x4 a5 = *(const i32x4*)(lds + cur + offA[5][ks]);
      i32x4 a6 = *(const i32x4*)(lds + cur + offA[6][ks]);
      i32x4 a7 = *(const i32x4*)(lds + cur + offA[7][ks]);
      unsigned w0 = *(const unsigned*)(lds + cur + offB[0][ks]);
      unsigned w1 = *(const unsigned*)(lds + cur + offB[1][ks]);
      i32x4 b0 = dec2(w0);
      i32x4 b1 = dec2(w1);
      __builtin_amdgcn_s_setprio(1);
      acc[0][0] = __builtin_amdgcn_mfma_i32_16x16x64_i8(a0, b0, acc[0][0], 0, 0, 0);
      acc[1][0] = __builtin_amdgcn_mfma_i32_16x16x64_i8(a1, b0, acc[1][0], 0, 0, 0);
      acc[2][0] = __builtin_amdgcn_mfma_i32_16x16x64_i8(a2, b0, acc[2][0], 0, 0, 0);
      acc[3][0] = __builtin_amdgcn_mfma_i32_16x16x64_i8(a3, b0, acc[3][0], 0, 0, 0);
      acc[4][0] = __builtin_amdgcn_mfma_i32_16x16x64_i8(a4, b0, acc[4][0], 0, 0, 0);
      acc[5][0] = __builtin_amdgcn_mfma_i32_16x16x64_i8(a5, b0, acc[5][0], 0, 0, 0);
      acc[6][0] = __builtin_amdgcn_mfma_i32_16x16x64_i8(a6, b0, acc[6][0], 0, 0, 0);
      acc[7][0] = __builtin_amdgcn_mfma_i32_16x16x64_i8(a7, b0, acc[7][0], 0, 0, 0);
      acc[0][1] = __builtin_amdgcn_mfma_i32_16x16x64_i8(a0, b1, acc[0][1], 0, 0, 0);
      acc[1][1] = __builtin_amdgcn_mfma_i32_16x16x64_i8(a1, b1, acc[1][1], 0, 0, 0);
      acc[2][1] = __builtin_amdgcn_mfma_i32_16x16x64_i8(a2, b1, acc[2][1], 0, 0, 0);
      acc[3][1] = __builtin_amdgcn_mfma_i32_16x16x64_i8(a3, b1, acc[3][1], 0, 0, 0);
      acc[4][1] = __builtin_amdgcn_mfma_i32_16x16x64_i8(a4, b1, acc[4][1], 0, 0, 0);
      acc[5][1] = __builtin_amdgcn_mfma_i32_16x16x64_i8(a5, b1, acc[5][1], 0, 0, 0);
      acc[6][1] = __builtin_amdgcn_mfma_i32_16x16x64_i8(a6, b1, acc[6][1], 0, 0, 0);
      acc[7][1] = __builtin_amdgcn_mfma_i32_16x16x64_i8(a7, b1, acc[7][1], 0, 0, 0);
      __builtin_amdgcn_s_setprio(0);
    }

    // next tile landed; publish block-wide, then swap
    asm volatile("s_waitcnt vmcnt(0)" ::: "memory");
    __builtin_amdgcn_s_barrier();

    const int tb = cur; cur = nxt; nxt = tb;
  }

  // Epilogue (validated R1-R12): C/D col = lane&15, row = (lane>>4)*4 + reg
  const int crow = sgrp * 4;
#pragma unroll
  for (int n = 0; n < 2; ++n) {
    const int col = brow0 + wc * 32 + n * 16 + rsub;
    const float sc = scale[col];
    const float bs = bias[col];
#pragma unroll
    for (int m = 0; m < 8; ++m) {
      const int r0 = arow0 + m * 16 + crow;
#pragma unroll
      for (int j = 0; j < 4; ++j) {
        out[(size_t)(r0 + j) * NDIM + col] = (float)acc[m][n][j] * sc + bs;
      }
    }
  }
}

extern "C" void kernel_launch(void* const* d_in, const int* in_sizes, int n_in,
                              void* d_out, int out_size, void* d_ws, size_t ws_size,
                              hipStream_t stream) {
  const int*   input  = (const int*)d_in[0];     // [2048][4096] int32
  const int*   weight = (const int*)d_in[1];     // [11008][4096] int32 in {-1,0,1}
  const float* scale  = (const float*)d_in[2];   // [11008]
  const float* bias   = (const float*)d_in[3];   // [11008]
  float*       out    = (float*)d_out;           // [2048][11008] fp32

  const size_t needA = (size_t)BATCH * KDIM;          // 8 MB int8

  char*     A8  = (char*)d_ws;
  unsigned* Bpk = (unsigned*)(A8 + needA);            // 11 MB 2-bit packed
  const int nA4 = (int)(needA / 4);
  convert_i32_i8<<<(nA4 + 255) / 256, 256, 0, stream>>>(input, (unsigned*)A8, nA4);
  convert_w2<<<NDIM * (KDIM / 16) / 256, 256, 0, stream>>>(weight, Bpk);

  const dim3 grid((BATCH / BM) * (NDIM / BN));   // 16 * 86 = 1376
  const dim3 block(256);
  ternary_gemm<<<grid, block, 0, stream>>>(A8, Bpk, scale, bias, out);
  (void)ws_size; (void)n_in; (void)in_sizes; (void)out_size;
}

// Round 14
// 138.210 us; speedup vs baseline: 1.2626x; 1.0166x over previous
//
#include <hip/hip_runtime.h>
#include <stdint.h>

#define BATCH   2048
#define KDIM    4096
#define NDIM    11008

#define BM 128
#define BN 128
#define BK 128
#define NT (KDIM / BK)               // 32 K-tiles
#define BPK_ROWB 1024                // packed B row bytes = KDIM/4

// LDS map: A dbuf 2x16KB at 0/16384; B 4-deep 4x4KB at 32768+4096*i; 48KB total
#define A0_OFF 0
#define A1_OFF 16384
#define B_BASE 32768

typedef __attribute__((ext_vector_type(4))) int i32x4;

typedef const __attribute__((address_space(1))) char glob_char;
typedef __attribute__((address_space(3))) char lds_char;

__device__ __forceinline__ unsigned pack4(i32x4 v) {
  return  ((unsigned)v.x & 0xFFu)
        | (((unsigned)v.y & 0xFFu) << 8)
        | (((unsigned)v.z & 0xFFu) << 16)
        | (((unsigned)v.w)         << 24);
}

// A: int32 (values in [-128,127]) -> packed int8, 4 elements per thread
__global__ __launch_bounds__(256) void convert_i32_i8(const int* __restrict__ src,
                                                      unsigned* __restrict__ dst,
                                                      int n4) {
  int idx = blockIdx.x * 256 + threadIdx.x;
  if (idx >= n4) return;
  i32x4 v = ((const i32x4*)src)[idx];
  dst[idx] = pack4(v);
}

// B: ternary int32 -> 2-bit packed (R12/R13-validated). Element e of word at
// bits [8*(e&3) + 2*(e>>2)]; LDS bank swizzle baked in: word i%8 stored at
// slot (i%8)^(row&7) within its 32B group.
__global__ __launch_bounds__(256) void convert_w2(const int* __restrict__ src,
                                                  unsigned* __restrict__ dst) {
  const int f = blockIdx.x * 256 + threadIdx.x;
  const int r = f >> 8;
  const int i = f & 255;
  const int* p = src + (size_t)r * KDIM + i * 16;
  unsigned w = 0;
#pragma unroll
  for (int e = 0; e < 16; ++e) {
    const unsigned v = (unsigned)p[e] & 3u;
    w |= v << (8 * (e & 3) + 2 * (e >> 2));
  }
  const int slot = (i & 7) ^ (r & 7);
  dst[(size_t)r * 256 + (i >> 3) * 8 + slot] = w;
}

// decode 16x 2-bit ternary -> 16 int8 (k-order): (x&M1) | ((y<<7)-y), y=x&M2
__device__ __forceinline__ i32x4 dec2(unsigned w) {
  const unsigned M1 = 0x01010101u, M2 = 0x02020202u;
  i32x4 r;
  { unsigned x = w;      unsigned y = x & M2; r.x = (int)((x & M1) | ((y << 7) - y)); }
  { unsigned x = w >> 2; unsigned y = x & M2; r.y = (int)((x & M1) | ((y << 7) - y)); }
  { unsigned x = w >> 4; unsigned y = x & M2; r.z = (int)((x & M1) | ((y << 7) - y)); }
  { unsigned x = w >> 6; unsigned y = x & M2; r.w = (int)((x & M1) | ((y << 7) - y)); }
  return r;
}

// C[2048][11008] = A[2048][4096] * W[11008][4096]^T via mfma_i32_16x16x64_i8.
// R14 = R13 (1m x 4n wave grid, 2-bit B, 3 blk/CU, fence-free skeleton) +
//  (a) ASYMMETRIC PREFETCH DEPTH: A depth-1 dbuf (L2-resident panel, short
//      latency), B depth-2 over 4 rotating 4KB buffers (HBM latency ~900cy
//      hidden under 2 KTs of compute). Issue order A(t+1)x4 then B(t+2);
//      ONE counted vmcnt(1) per KT retires {B(t+1), A(t+1)x4} and leaves
//      B(t+2) in flight (FIFO) -> staging pipe never drains for B.
//  (b) t-loop unrolled x4 -> all LDS buffer bases are compile-time ds_read
//      offset immediates (zero addressing VALU in the hot path).
// Everything else R13-identical: 4.77e-3 staged B/op, G=16x86=1376,
// 4-wide mt-supertile XCD raster, A 8-slot swizzle on global source,
// B swizzle baked into packed layout, validated epilogue.
__global__ __launch_bounds__(256, 3) void ternary_gemm(const char* __restrict__ A8,
                                                       const unsigned* __restrict__ B2,
                                                       const float* __restrict__ scale,
                                                       const float* __restrict__ bias,
                                                       float* __restrict__ out) {
  __shared__ char lds[49152];          // 48KB -> 3 blocks/CU

  const int tid  = threadIdx.x;
  const int wid  = tid >> 6;
  const int lane = tid & 63;

  // XCD swizzle (1376 % 8 == 0 -> bijective) + 4-wide mt-supertile raster
  const int wg  = (blockIdx.x & 7) * 172 + (blockIdx.x >> 3);
  const int mtq = wg / 344;
  const int r   = wg - mtq * 344;
  const int nt  = r >> 2;
  const int mt  = mtq * 4 + (r & 3);
  const int arow0 = mt * BM;
  const int brow0 = nt * BN;

  const int wc = wid;                  // 0..3 : 32-col slice (unique B per wave)
  const int rsub = lane & 15;
  const int sgrp = lane >> 4;

  // A staging: 4 rounds of 256 thr x 16B (32 rows of 128B each)
  const int srowA = tid >> 3;
  const int slotA = (tid & 7) ^ (srowA & 7);
  // B staging: 1 round of 256 thr x 16B (128 rows of 32B), linear copy
  const int srowB = tid >> 1;
  const int shalfB = (tid & 1) * 16;

  const char* gAbase = A8 + (size_t)(arow0 + srowA) * KDIM + slotA * 16;
  const char* gBbase = (const char*)B2 + (size_t)(brow0 + srowB) * BPK_ROWB + shalfB;

  auto stageA = [&](int Adst, int kt) {
#pragma unroll
    for (int rr = 0; rr < 4; ++rr) {
      __builtin_amdgcn_global_load_lds(
          (glob_char*)(gAbase + (size_t)rr * 32 * KDIM + kt * BK),
          (lds_char*)(lds + Adst + rr * 4096 + wid * 1024), 16, 0, 0);
    }
  };
  auto stageB = [&](int Bdst, int kt) {
    __builtin_amdgcn_global_load_lds(
        (glob_char*)(gBbase + kt * (BK / 4)),
        (lds_char*)(lds + Bdst + wid * 1024), 16, 0, 0);
  };

  // loop-invariant fragment byte-offsets (buffer-relative)
  int offA[8][2], offB[2][2];
#pragma unroll
  for (int m = 0; m < 8; ++m) {
    const int row = m * 16 + rsub;
#pragma unroll
    for (int ks = 0; ks < 2; ++ks) {
      const int p = (ks * 4 + sgrp) ^ (row & 7);
      offA[m][ks] = row * 128 + p * 16;
    }
  }
#pragma unroll
  for (int n = 0; n < 2; ++n) {
    const int row = wc * 32 + n * 16 + rsub;
#pragma unroll
    for (int ks = 0; ks < 2; ++ks) {
      const int p = (ks * 4 + sgrp) ^ (row & 7);
      offB[n][ks] = row * 32 + p * 4;
    }
  }

  i32x4 acc[8][2];
#pragma unroll
  for (int m = 0; m < 8; ++m)
#pragma unroll
    for (int n = 0; n < 2; ++n)
      acc[m][n] = (i32x4){0, 0, 0, 0};

  // prologue: A(0)->A0, B(0)->B0, B(1)->B1; full drain once
  stageA(A0_OFF, 0);
  stageB(B_BASE, 0);
  stageB(B_BASE + 4096, 1);
  asm volatile("s_waitcnt vmcnt(0)" ::: "memory");
  __builtin_amdgcn_s_barrier();

  // one K-step: stage A(t+1)->Anxt, B(t+2)->Bpf; compute from Acur/Bcur;
  // vmcnt(1) retires {B(t+1), A(t+1)x4}, leaves B(t+2) in flight; barrier.
  auto step = [&](int Acur, int Anxt, int Bcur, int Bpf, int t) {
    const int ktA = (t + 1 < NT) ? t + 1 : NT - 1;
    const int ktB = (t + 2 < NT) ? t + 2 : NT - 1;
    stageA(Anxt, ktA);
    stageB(Bpf, ktB);
#pragma unroll
    for (int ks = 0; ks < 2; ++ks) {
      i32x4 a0 = *(const i32x4*)(lds + Acur + offA[0][ks]);
      i32x4 a1 = *(const i32x4*)(lds + Acur + offA[1][ks]);
      i32x4 a2 = *(const i32x4*)(lds + Acur + offA[2][ks]);
      i32x4 a3 = *(const i32x4*)(lds + Acur + offA[3][ks]);
      i32x4 a4 = *(const i32x4*)(lds + Acur + offA[4][ks]);
      i32x4 a5 = *(const i32x4*)(lds + Acur + offA[5][ks]);
      i32x4 a6 = *(const i32x4*)(lds + Acur + offA[6][ks]);
      i32x4 a7 = *(const i32x4*)(lds + Acur + offA[7][ks]);
      unsigned w0 = *(const unsigned*)(lds + Bcur + offB[0][ks]);
      unsigned w1 = *(const unsigned*)(lds + Bcur + offB[1][ks]);
      i32x4 b0 = dec2(w0);
      i32x4 b1 = dec2(w1);
      __builtin_amdgcn_s_setprio(1);
      acc[0][0] = __builtin_amdgcn_mfma_i32_16x16x64_i8(a0, b0, acc[0][0], 0, 0, 0);
      acc[1][0] = __builtin_amdgcn_mfma_i32_16x16x64_i8(a1, b0, acc[1][0], 0, 0, 0);
      acc[2][0] = __builtin_amdgcn_mfma_i32_16x16x64_i8(a2, b0, acc[2][0], 0, 0, 0);
      acc[3][0] = __builtin_amdgcn_mfma_i32_16x16x64_i8(a3, b0, acc[3][0], 0, 0, 0);
      acc[4][0] = __builtin_amdgcn_mfma_i32_16x16x64_i8(a4, b0, acc[4][0], 0, 0, 0);
      acc[5][0] = __builtin_amdgcn_mfma_i32_16x16x64_i8(a5, b0, acc[5][0], 0, 0, 0);
      acc[6][0] = __builtin_amdgcn_mfma_i32_16x16x64_i8(a6, b0, acc[6][0], 0, 0, 0);
      acc[7][0] = __builtin_amdgcn_mfma_i32_16x16x64_i8(a7, b0, acc[7][0], 0, 0, 0);
      acc[0][1] = __builtin_amdgcn_mfma_i32_16x16x64_i8(a0, b1, acc[0][1], 0, 0, 0);
      acc[1][1] = __builtin_amdgcn_mfma_i32_16x16x64_i8(a1, b1, acc[1][1], 0, 0, 0);
      acc[2][1] = __builtin_amdgcn_mfma_i32_16x16x64_i8(a2, b1, acc[2][1], 0, 0, 0);
      acc[3][1] = __builtin_amdgcn_mfma_i32_16x16x64_i8(a3, b1, acc[3][1], 0, 0, 0);
      acc[4][1] = __builtin_amdgcn_mfma_i32_16x16x64_i8(a4, b1, acc[4][1], 0, 0, 0);
      acc[5][1] = __builtin_amdgcn_mfma_i32_16x16x64_i8(a5, b1, acc[5][1], 0, 0, 0);
      acc[6][1] = __builtin_amdgcn_mfma_i32_16x16x64_i8(a6, b1, acc[6][1], 0, 0, 0);
      acc[7][1] = __builtin_amdgcn_mfma_i32_16x16x64_i8(a7, b1, acc[7][1], 0, 0, 0);
      __builtin_amdgcn_s_setprio(0);
    }
    asm volatile("s_waitcnt vmcnt(1)" ::: "memory");
    __builtin_amdgcn_s_barrier();
  };

  for (int t4 = 0; t4 < NT; t4 += 4) {
    step(A0_OFF, A1_OFF, B_BASE,         B_BASE +  8192, t4);
    step(A1_OFF, A0_OFF, B_BASE +  4096, B_BASE + 12288, t4 + 1);
    step(A0_OFF, A1_OFF, B_BASE +  8192, B_BASE,         t4 + 2);
    step(A1_OFF, A0_OFF, B_BASE + 12288, B_BASE +  4096, t4 + 3);
  }

  // Epilogue (validated R1-R13): C/D col = lane&15, row = (lane>>4)*4 + reg
  const int crow = sgrp * 4;
#pragma unroll
  for (int n = 0; n < 2; ++n) {
    const int col = brow0 + wc * 32 + n * 16 + rsub;
    const float sc = scale[col];
    const float bs = bias[col];
#pragma unroll
    for (int m = 0; m < 8; ++m) {
      const int r0 = arow0 + m * 16 + crow;
#pragma unroll
      for (int j = 0; j < 4; ++j) {
        out[(size_t)(r0 + j) * NDIM + col] = (float)acc[m][n][j] * sc + bs;
      }
    }
  }
}

extern "C" void kernel_launch(void* const* d_in, const int* in_sizes, int n_in,
                              void* d_out, int out_size, void* d_ws, size_t ws_size,
                              hipStream_t stream) {
  const int*   input  = (const int*)d_in[0];     // [2048][4096] int32
  const int*   weight = (const int*)d_in[1];     // [11008][4096] int32 in {-1,0,1}
  const float* scale  = (const float*)d_in[2];   // [11008]
  const float* bias   = (const float*)d_in[3];   // [11008]
  float*       out    = (float*)d_out;           // [2048][11008] fp32

  const size_t needA = (size_t)BATCH * KDIM;          // 8 MB int8

  char*     A8  = (char*)d_ws;
  unsigned* Bpk = (unsigned*)(A8 + needA);            // 11 MB 2-bit packed
  const int nA4 = (int)(needA / 4);
  convert_i32_i8<<<(nA4 + 255) / 256, 256, 0, stream>>>(input, (unsigned*)A8, nA4);
  convert_w2<<<NDIM * (KDIM / 16) / 256, 256, 0, stream>>>(weight, Bpk);

  const dim3 grid((BATCH / BM) * (NDIM / BN));   // 16 * 86 = 1376
  const dim3 block(256);
  ternary_gemm<<<grid, block, 0, stream>>>(A8, Bpk, scale, bias, out);
  (void)ws_size; (void)n_in; (void)in_sizes; (void)out_size;
}